// Round 3
// baseline (1621.765 us; speedup 1.0000x reference)
//
#include <hip/hip_runtime.h>

static constexpr int NBRS = 21;
static constexpr int Nv   = 12288;
static constexpr int BV   = 4 * Nv;            // 49152 rows
static constexpr float BN_EPS = 1e-5f;

// ---------------- SPMM (C=8, scalar)
template<bool CHEB2>
__global__ void spmm8_kernel(float* __restrict__ y, const float* __restrict__ x,
                             const float* __restrict__ x0,
                             const float* __restrict__ val, const int* __restrict__ col)
{
    int idx = blockIdx.x * 256 + threadIdx.x;
    int c = idx % 8;
    int v = (idx / 8) % Nv;
    int b = idx / (8 * Nv);
    int e0 = v * NBRS;
    float acc = 0.f;
    #pragma unroll
    for (int j = 0; j < NBRS; ++j) {
        int u = col[e0 + j];
        acc = fmaf(val[e0 + j], x[((size_t)b * Nv + u) * 8 + c], acc);
    }
    if (CHEB2) y[idx] = 2.f * acc - x0[idx];
    else       y[idx] = acc;
}

// ---------------- SPMM C=64, float4, optional fused BN+relu on gather and/or x0
template<bool CHEB2, bool BNG, bool BNX0>
__global__ __launch_bounds__(256)
void spmm64_kernel(float* __restrict__ y, const float* __restrict__ x,
                   const float* __restrict__ x0,
                   const float* __restrict__ val, const int* __restrict__ col,
                   const float* __restrict__ bn_a, const float* __restrict__ bn_b)
{
    int idx = blockIdx.x * 256 + threadIdx.x;   // over BV*16
    int q = idx % 16;
    int v = (idx / 16) % Nv;
    int b = idx / (16 * Nv);
    int e0 = v * NBRS;
    const float4* x4 = (const float4*)x;
    float4 a4, b4;
    if (BNG || (CHEB2 && BNX0)) {
        a4 = ((const float4*)bn_a)[q];
        b4 = ((const float4*)bn_b)[q];
    }
    float4 acc = {0.f, 0.f, 0.f, 0.f};
    #pragma unroll
    for (int j = 0; j < NBRS; ++j) {
        int u = col[e0 + j];
        float a = val[e0 + j];
        float4 xv = x4[(size_t)(b * Nv + u) * 16 + q];
        if (BNG) {
            xv.x = fmaxf(fmaf(xv.x, a4.x, b4.x), 0.f);
            xv.y = fmaxf(fmaf(xv.y, a4.y, b4.y), 0.f);
            xv.z = fmaxf(fmaf(xv.z, a4.z, b4.z), 0.f);
            xv.w = fmaxf(fmaf(xv.w, a4.w, b4.w), 0.f);
        }
        acc.x = fmaf(a, xv.x, acc.x);
        acc.y = fmaf(a, xv.y, acc.y);
        acc.z = fmaf(a, xv.z, acc.z);
        acc.w = fmaf(a, xv.w, acc.w);
    }
    if (CHEB2) {
        float4 pv = ((const float4*)x0)[idx];
        if (BNX0) {
            pv.x = fmaxf(fmaf(pv.x, a4.x, b4.x), 0.f);
            pv.y = fmaxf(fmaf(pv.y, a4.y, b4.y), 0.f);
            pv.z = fmaxf(fmaf(pv.z, a4.z, b4.z), 0.f);
            pv.w = fmaxf(fmaf(pv.w, a4.w, b4.w), 0.f);
        }
        acc.x = 2.f * acc.x - pv.x;
        acc.y = 2.f * acc.y - pv.y;
        acc.z = 2.f * acc.z - pv.z;
        acc.w = 2.f * acc.w - pv.w;
    }
    ((float4*)y)[idx] = acc;
}

// ---------------- Register-blocked GEMM, no LDS for x (L1-broadcast row loads).
// out[m, o] = sum_ki x[m, ki] * w[ki, o] (+bias). Optional fused BN+relu on x0
// during load; optional fused BN-stats (sum, sumsq per channel) to partial.
// PACKOUT: FOUT=32 packed conv3 (3 z-outputs of 8 channels, 4th column dummy).
template<int FOUT, int KFIN, int FIN, int OTHR, int RGRP, int RPG, int NSRC,
         bool STATS, bool BN0, bool HAS_BIAS, bool PACKOUT>
__global__ __launch_bounds__(OTHR * RGRP)
void gemm_rb_kernel(const float* __restrict__ x0, const float* __restrict__ x1,
                    const float* __restrict__ x2,
                    const float* __restrict__ w, const float* __restrict__ bias,
                    const float* __restrict__ bn_a, const float* __restrict__ bn_b,
                    float* __restrict__ out, float2* __restrict__ partial)
{
    constexpr int TO = 8;
    constexpr int THREADS = OTHR * RGRP;
    constexpr int ROWS = RGRP * RPG;
    __shared__ float2 red[STATS ? RGRP : 1][STATS ? FOUT : 1];

    const int tid  = threadIdx.x;
    const int othr = tid % OTHR;
    const int grp  = tid / OTHR;
    const int m0 = blockIdx.x * ROWS;
    const int r0 = grp * RPG;
    const int o0 = othr * TO;

    float acc[RPG][TO];
    #pragma unroll
    for (int r = 0; r < RPG; ++r)
        #pragma unroll
        for (int t = 0; t < TO; ++t) acc[r][t] = 0.f;

    #pragma unroll 2
    for (int k4 = 0; k4 < KFIN / 4; ++k4) {
        const int ki = k4 * 4;
        const float* src;
        int i;
        if constexpr (NSRC == 1) { src = x0; i = ki; }
        else {
            const int kk = ki / FIN;
            i = ki % FIN;
            src = (kk == 0) ? x0 : (kk == 1 ? x1 : x2);
        }
        float xv[RPG][4];
        #pragma unroll
        for (int r = 0; r < RPG; ++r) {
            const float4 t4 = *reinterpret_cast<const float4*>(src + (size_t)(m0 + r0 + r) * FIN + i);
            xv[r][0] = t4.x; xv[r][1] = t4.y; xv[r][2] = t4.z; xv[r][3] = t4.w;
        }
        if constexpr (BN0) {
            if (NSRC == 1 || ki < FIN) {
                const float4 a4 = *reinterpret_cast<const float4*>(bn_a + i);
                const float4 b4 = *reinterpret_cast<const float4*>(bn_b + i);
                const float aa[4] = {a4.x, a4.y, a4.z, a4.w};
                const float bb[4] = {b4.x, b4.y, b4.z, b4.w};
                #pragma unroll
                for (int r = 0; r < RPG; ++r)
                    #pragma unroll
                    for (int j = 0; j < 4; ++j)
                        xv[r][j] = fmaxf(fmaf(xv[r][j], aa[j], bb[j]), 0.f);
            }
        }
        #pragma unroll
        for (int j = 0; j < 4; ++j) {
            const float4 wa = *reinterpret_cast<const float4*>(w + (size_t)(ki + j) * FOUT + o0);
            const float4 wb = *reinterpret_cast<const float4*>(w + (size_t)(ki + j) * FOUT + o0 + 4);
            const float wv[8] = {wa.x, wa.y, wa.z, wa.w, wb.x, wb.y, wb.z, wb.w};
            #pragma unroll
            for (int r = 0; r < RPG; ++r) {
                const float xx = xv[r][j];
                #pragma unroll
                for (int t = 0; t < TO; ++t) acc[r][t] = fmaf(xx, wv[t], acc[r][t]);
            }
        }
    }

    float bv[TO];
    if constexpr (HAS_BIAS) {
        const float4 ba = *reinterpret_cast<const float4*>(bias + o0);
        const float4 bb2 = *reinterpret_cast<const float4*>(bias + o0 + 4);
        bv[0] = ba.x; bv[1] = ba.y; bv[2] = ba.z; bv[3] = ba.w;
        bv[4] = bb2.x; bv[5] = bb2.y; bv[6] = bb2.z; bv[7] = bb2.w;
    } else {
        #pragma unroll
        for (int t = 0; t < TO; ++t) bv[t] = 0.f;
    }

    float s[TO], q[TO];
    #pragma unroll
    for (int t = 0; t < TO; ++t) { s[t] = 0.f; q[t] = 0.f; }

    #pragma unroll
    for (int r = 0; r < RPG; ++r) {
        float v[TO];
        #pragma unroll
        for (int t = 0; t < TO; ++t) {
            v[t] = acc[r][t] + bv[t];
            if constexpr (STATS) { s[t] += v[t]; q[t] = fmaf(v[t], v[t], q[t]); }
        }
        const int m = m0 + r0 + r;
        const float4 oA = make_float4(v[0], v[1], v[2], v[3]);
        const float4 oB = make_float4(v[4], v[5], v[6], v[7]);
        if constexpr (PACKOUT) {
            if (othr < 3) {
                float* dst = out + ((size_t)othr * BV + m) * 8;
                *reinterpret_cast<float4*>(dst)     = oA;
                *reinterpret_cast<float4*>(dst + 4) = oB;
            }
        } else {
            float* dst = out + (size_t)m * FOUT + o0;
            *reinterpret_cast<float4*>(dst)     = oA;
            *reinterpret_cast<float4*>(dst + 4) = oB;
        }
    }

    if constexpr (STATS) {
        #pragma unroll
        for (int t = 0; t < TO; ++t) red[grp][o0 + t] = make_float2(s[t], q[t]);
        __syncthreads();
        for (int c = tid; c < FOUT; c += THREADS) {
            float rs = 0.f, rq = 0.f;
            for (int g = 0; g < RGRP; ++g) { float2 p = red[g][c]; rs += p.x; rq += p.y; }
            partial[(size_t)blockIdx.x * FOUT + c] = make_float2(rs, rq);
        }
    }
}

// ---------------- BN finalize: reduce per-block partials -> per-channel (a, b)
template<int C>
__global__ __launch_bounds__(1024)
void bn_finalize_kernel(const float2* __restrict__ partial,
                        const float* __restrict__ g, const float* __restrict__ b,
                        float* __restrict__ a_out, float* __restrict__ b_out,
                        float invN, int nblk)
{
    constexpr int G = 1024 / C;
    int c  = threadIdx.x / G;
    int gg = threadIdx.x % G;
    float s = 0.f, ss = 0.f;
    for (int k = gg; k < nblk; k += G) {
        float2 p = partial[(size_t)k * C + c];
        s += p.x; ss += p.y;
    }
    #pragma unroll
    for (int off = G / 2; off > 0; off >>= 1) {
        s  += __shfl_down(s, off);
        ss += __shfl_down(ss, off);
    }
    if (gg == 0) {
        float m = s * invN;
        float var = ss * invN - m * m;
        float a = g[c] * rsqrtf(var + BN_EPS);
        a_out[c] = a;
        b_out[c] = b[c] - m * a;
    }
}

// ---------------- BN apply (float4), for C=256 tensors only
template<int C, bool RELU, bool ADD>
__global__ __launch_bounds__(256)
void bn_apply_kernel(float* __restrict__ out, const float* __restrict__ x,
                     const float* __restrict__ base,
                     const float* __restrict__ bn_a, const float* __restrict__ bn_b)
{
    int i = blockIdx.x * 256 + threadIdx.x;   // float4 index
    float4 v = ((const float4*)x)[i];
    int c0 = (i * 4) % C;
    float4 a4 = *reinterpret_cast<const float4*>(bn_a + c0);
    float4 b4 = *reinterpret_cast<const float4*>(bn_b + c0);
    float4 r;
    r.x = fmaf(v.x, a4.x, b4.x);
    r.y = fmaf(v.y, a4.y, b4.y);
    r.z = fmaf(v.z, a4.z, b4.z);
    r.w = fmaf(v.w, a4.w, b4.w);
    if (ADD) {
        float4 bvv = ((const float4*)base)[i];
        r.x += bvv.x; r.y += bvv.y; r.z += bvv.z; r.w += bvv.w;
    }
    if (RELU) {
        r.x = fmaxf(r.x, 0.f); r.y = fmaxf(r.y, 0.f);
        r.z = fmaxf(r.z, 0.f); r.w = fmaxf(r.w, 0.f);
    }
    ((float4*)out)[i] = r;
}

// ---------------- conv3 weight packer: [3][256][8] -> [256][32] (+ padded bias)
__global__ void pack_conv3_kernel(const float* __restrict__ w, const float* __restrict__ bias,
                                  float* __restrict__ wpack, float* __restrict__ bpack)
{
    int t = blockIdx.x * 256 + threadIdx.x;
    if (t < 256 * 32) {
        int ki = t / 32, c = t % 32;
        int j = c / 8, o = c % 8;
        wpack[t] = (j < 3) ? w[(size_t)j * 2048 + ki * 8 + o] : 0.f;
    }
    if (t < 32) bpack[t] = (t < 8) ? bias[t] : 0.f;
}

// ---------------- conv3 tail helpers
__global__ void combine_kernel(float* __restrict__ e, const float* __restrict__ z1,
                               const float* __restrict__ t)
{
    int i = blockIdx.x * 256 + threadIdx.x;
    e[i] = fmaf(2.f, t[i], z1[i]);
}

__global__ void final_add_kernel(float* __restrict__ out, const float* __restrict__ z0,
                                 const float* __restrict__ z2, const float* __restrict__ s)
{
    int i = blockIdx.x * 256 + threadIdx.x;
    out[i] = z0[i] - z2[i] + s[i];
}

extern "C" void kernel_launch(void* const* d_in, const int* in_sizes, int n_in,
                              void* d_out, int out_size, void* d_ws, size_t ws_size,
                              hipStream_t stream)
{
    const float* x       = (const float*)d_in[0];
    const int*   col     = (const int*)  d_in[2];
    const float* eval_   = (const float*)d_in[3];
    const float* conv1_w = (const float*)d_in[4];
    const float* conv1_b = (const float*)d_in[5];
    const float* bn1_g   = (const float*)d_in[6];
    const float* bn1_b   = (const float*)d_in[7];
    const float* conv2_w = (const float*)d_in[8];
    const float* conv2_b = (const float*)d_in[9];
    const float* bn2_g   = (const float*)d_in[10];
    const float* bn2_b   = (const float*)d_in[11];
    const float* bt_c1w  = (const float*)d_in[12];
    const float* bt_c1b  = (const float*)d_in[13];
    const float* bt_c2w  = (const float*)d_in[14];
    const float* bt_c2b  = (const float*)d_in[15];
    const float* bt_c3w  = (const float*)d_in[16];
    const float* bt_c3b  = (const float*)d_in[17];
    const float* btbn1g  = (const float*)d_in[18];
    const float* btbn1b  = (const float*)d_in[19];
    const float* btbn2g  = (const float*)d_in[20];
    const float* btbn2b  = (const float*)d_in[21];
    const float* btbn3g  = (const float*)d_in[22];
    const float* btbn3b  = (const float*)d_in[23];
    const float* conv3_w = (const float*)d_in[24];
    const float* conv3_b = (const float*)d_in[25];
    float* out = (float*)d_out;

    float* ws = (float*)d_ws;
    float* h2    = ws;                         // BV*256
    float* y3    = h2 + (size_t)BV * 256;      // BV*256 (also aliased as GEMM stats partial)
    float* t64a  = y3 + (size_t)BV * 256;      // BV*64
    float* t64b  = t64a + (size_t)BV * 64;     // BV*64
    float* t64c  = t64b + (size_t)BV * 64;     // BV*64
    float* t64d  = t64c + (size_t)BV * 64;     // BV*64
    float* aarr  = t64d + (size_t)BV * 64;     // 11*256
    float* barr  = aarr + 11 * 256;            // 11*256
    float* wpack = barr + 11 * 256;            // 256*32
    float* bpack = wpack + 256 * 32;           // 32
    float2* partY = (float2*)y3;               // partial when y3 is dead
    float2* partC = (float2*)t64c;             // partial for cheb3 (y3 being written)

    const float invN = 1.f / (float)BV;

    // ---------- Stage A: conv1 (8 -> 64), K=3 ----------
    spmm8_kernel<false><<<BV * 8 / 256, 256, 0, stream>>>(t64a, x, nullptr, eval_, col);
    spmm8_kernel<true ><<<BV * 8 / 256, 256, 0, stream>>>(t64b, t64a, x, eval_, col);
    gemm_rb_kernel<64, 24, 8, 8, 32, 4, 3, true, false, true, false>
        <<<BV / 128, 256, 0, stream>>>(x, t64a, t64b, conv1_w, conv1_b, nullptr, nullptr, t64c, partY);
    bn_finalize_kernel<64><<<1, 1024, 0, stream>>>(partY, bn1_g, bn1_b, aarr, barr, invN, BV / 128);

    // ---------- Stage B: conv2 (64 -> 256), K=3, x0-BN fused ----------
    spmm64_kernel<false, true, false><<<BV * 16 / 256, 256, 0, stream>>>(t64a, t64c, nullptr, eval_, col, aarr, barr);
    spmm64_kernel<true, false, true ><<<BV * 16 / 256, 256, 0, stream>>>(t64b, t64a, t64c, eval_, col, aarr, barr);
    gemm_rb_kernel<256, 192, 64, 32, 8, 8, 3, true, true, true, false>
        <<<BV / 64, 256, 0, stream>>>(t64c, t64a, t64b, conv2_w, conv2_b, aarr, barr, h2, partY);
    bn_finalize_kernel<256><<<1, 1024, 0, stream>>>(partY, bn2_g, bn2_b, aarr + 256, barr + 256, invN, BV / 64);
    bn_apply_kernel<256, true, false><<<BV, 256, 0, stream>>>(h2, h2, nullptr, aarr + 256, barr + 256);

    // ---------- Stage C: 3 bottlenecks ----------
    for (int i = 0; i < 3; ++i) {
        float* aA = aarr + (2 + i * 3) * 256; float* bA = barr + (2 + i * 3) * 256;
        float* aB = aarr + (3 + i * 3) * 256; float* bB = barr + (3 + i * 3) * 256;
        float* aC = aarr + (4 + i * 3) * 256; float* bC = barr + (4 + i * 3) * 256;

        // cheb1: K=1, 256->64, stats fused
        gemm_rb_kernel<64, 256, 256, 8, 32, 4, 1, true, false, true, false>
            <<<BV / 128, 256, 0, stream>>>(h2, nullptr, nullptr,
                                           bt_c1w + (size_t)i * 256 * 64, bt_c1b + i * 64,
                                           nullptr, nullptr, t64c, partY);
        bn_finalize_kernel<64><<<1, 1024, 0, stream>>>(partY, btbn1g + i * 64, btbn1b + i * 64, aA, bA, invN, BV / 128);

        // cheb2: K=3, 64->64; BN1 fused into gathers and x0-staging
        spmm64_kernel<false, true, false><<<BV * 16 / 256, 256, 0, stream>>>(t64a, t64c, nullptr, eval_, col, aA, bA);
        spmm64_kernel<true, false, true ><<<BV * 16 / 256, 256, 0, stream>>>(t64b, t64a, t64c, eval_, col, aA, bA);
        gemm_rb_kernel<64, 192, 64, 8, 32, 4, 3, true, true, true, false>
            <<<BV / 128, 256, 0, stream>>>(t64c, t64a, t64b,
                                           bt_c2w + (size_t)i * 3 * 64 * 64, bt_c2b + i * 64,
                                           aA, bA, t64d, partY);
        bn_finalize_kernel<64><<<1, 1024, 0, stream>>>(partY, btbn2g + i * 64, btbn2b + i * 64, aB, bB, invN, BV / 128);

        // cheb3: K=1, 64->256; BN2 fused into x0-staging; stats fused (partial -> t64c)
        gemm_rb_kernel<256, 64, 64, 32, 8, 8, 1, true, true, true, false>
            <<<BV / 64, 256, 0, stream>>>(t64d, nullptr, nullptr,
                                          bt_c3w + (size_t)i * 64 * 256, bt_c3b + i * 256,
                                          aB, bB, y3, partC);
        bn_finalize_kernel<256><<<1, 1024, 0, stream>>>(partC, btbn3g + i * 256, btbn3b + i * 256, aC, bC, invN, BV / 64);
        // BN3 apply + residual add into h2
        bn_apply_kernel<256, false, true><<<BV, 256, 0, stream>>>(h2, y3, h2, aC, bC);
    }

    // ---------- Stage D: conv3 (256 -> 8), K=3, commuted: out = z0 - z2 + L(z1 + 2*L*z2) ----------
    float* z0 = t64a;
    float* z1 = z0 + (size_t)BV * 8;
    float* z2 = z1 + (size_t)BV * 8;
    float* tt = z2 + (size_t)BV * 8;
    float* ee = tt + (size_t)BV * 8;
    float* sb = ee + (size_t)BV * 8;

    pack_conv3_kernel<<<32, 256, 0, stream>>>(conv3_w, conv3_b, wpack, bpack);
    gemm_rb_kernel<32, 256, 256, 4, 64, 4, 1, false, false, true, true>
        <<<BV / 256, 256, 0, stream>>>(h2, nullptr, nullptr, wpack, bpack, nullptr, nullptr, z0, nullptr);

    spmm8_kernel<false><<<BV * 8 / 256, 256, 0, stream>>>(tt, z2, nullptr, eval_, col);
    combine_kernel<<<BV * 8 / 256, 256, 0, stream>>>(ee, z1, tt);
    spmm8_kernel<false><<<BV * 8 / 256, 256, 0, stream>>>(sb, ee, nullptr, eval_, col);
    final_add_kernel<<<BV * 8 / 256, 256, 0, stream>>>(out, z0, z2, sb);

    (void)in_sizes; (void)n_in; (void)out_size; (void)ws_size;
}